// Round 4
// baseline (328.169 us; speedup 1.0000x reference)
//
#include <hip/hip_runtime.h>
#include <hip/hip_bf16.h>
#include <stdint.h>

// ---------------------------------------------------------------------------
// MHA forward, B=2 S=2048 E=1024 H=16 D=64, fp32 in/out, bf16 MFMA internally.
// cvt+pack(8 seg) -> QKV proj GEMM (z=3; z==2 writes V transposed) ->
// flash attention (LDS dbuf K/V, swizzled, swapped QK^T, fixed-m exp2 softmax)
// -> out proj (128x64 tiles).
// ---------------------------------------------------------------------------

typedef __bf16 bf16x8 __attribute__((ext_vector_type(8)));
typedef __bf16 bf16x4 __attribute__((ext_vector_type(4)));
typedef float  f32x4  __attribute__((ext_vector_type(4)));
typedef unsigned int u32x4 __attribute__((ext_vector_type(4)));

#define MFMA16(a, b, c) __builtin_amdgcn_mfma_f32_16x16x32_bf16((a), (b), (c), 0, 0, 0)

#if __has_builtin(__builtin_amdgcn_exp2f)
#define EXP2(x) __builtin_amdgcn_exp2f(x)
#else
#define EXP2(x) exp2f(x)
#endif

static constexpr int kB = 2, kS = 2048, kE = 1024, kH = 16, kD = 64;
static constexpr int kM = kB * kS;                // 4096 rows
static constexpr int kMaskWordsPerRow = kS / 64;  // 32
static constexpr float kLog2e = 1.4426950408889634f;

// ---- async global->LDS (16B per lane, wave-uniform LDS base) --------------
__device__ __forceinline__ void gload_lds16(const void* g, void* l) {
  __builtin_amdgcn_global_load_lds(
      (const __attribute__((address_space(1))) unsigned int*)g,
      (__attribute__((address_space(3))) unsigned int*)l, 16, 0, 0);
}

__device__ __forceinline__ unsigned pack_bf16x2(float a, float b) {
  unsigned short lo = __builtin_bit_cast(unsigned short, (__bf16)a);
  unsigned short hi = __builtin_bit_cast(unsigned short, (__bf16)b);
  return (unsigned)lo | ((unsigned)hi << 16);
}

// ---------------------------------------------------------------------------
// Kernel 1: z=0..6: f32->bf16 cvt of q,k,v,Wq,Wk,Wv,Wo; z=7: mask bit-pack.
// ---------------------------------------------------------------------------
__global__ __launch_bounds__(256) void cvt_pack_kernel(
    const float* __restrict__ q, const float* __restrict__ k, const float* __restrict__ v,
    const float* __restrict__ wq, const float* __restrict__ wk,
    const float* __restrict__ wv, const float* __restrict__ wo,
    const int* __restrict__ mask,
    __bf16* __restrict__ qb, __bf16* __restrict__ kb, __bf16* __restrict__ vb,
    __bf16* __restrict__ wqb, __bf16* __restrict__ wkb,
    __bf16* __restrict__ wvb, __bf16* __restrict__ wob,
    unsigned long long* __restrict__ mw) {
  const int z = blockIdx.y;
  if (z == 7) {
    const int lane = threadIdx.x & 63;
    const int wid = (blockIdx.x * blockDim.x + threadIdx.x) >> 6;
    const int nwaves = (gridDim.x * blockDim.x) >> 6;
    const int nwords = kB * kS * kMaskWordsPerRow;  // 131072
    for (int w = wid; w < nwords; w += nwaves) {
      int mv = mask[(size_t)w * 64 + lane];
      unsigned long long bits = __ballot(mv != 0);
      if (lane == 0) mw[w] = bits;
    }
    return;
  }
  const float* src; __bf16* dst; int n;
  switch (z) {
    case 0: src = q;  dst = qb;  n = kM * kE; break;
    case 1: src = k;  dst = kb;  n = kM * kE; break;
    case 2: src = v;  dst = vb;  n = kM * kE; break;
    case 3: src = wq; dst = wqb; n = kE * kE; break;
    case 4: src = wk; dst = wkb; n = kE * kE; break;
    case 5: src = wv; dst = wvb; n = kE * kE; break;
    default: src = wo; dst = wob; n = kE * kE; break;
  }
  const int n4 = n >> 2;
  const int stride = gridDim.x * blockDim.x;
  for (int i = blockIdx.x * blockDim.x + threadIdx.x; i < n4; i += stride) {
    float4 f = ((const float4*)src)[i];
    bf16x4 o = {(__bf16)f.x, (__bf16)f.y, (__bf16)f.z, (__bf16)f.w};
    ((bf16x4*)dst)[i] = o;
  }
}

// ---------------------------------------------------------------------------
// Kernel 2: C = A[4096,1024] @ W^T + bias (NT, bf16 MFMA), 128x128 tile.
// z=0: -> Qh [B,H,S,D] scaled by (1/8)*log2e; z=1: -> Kh [B,H,S,D];
// z=2: -> Vt [B,H,D,S] via LDS-bounced transposed epilogue.
// ---------------------------------------------------------------------------
__global__ __launch_bounds__(256) void gemm_bt(
    const __bf16* __restrict__ A0, const __bf16* __restrict__ A1, const __bf16* __restrict__ A2,
    const __bf16* __restrict__ W0, const __bf16* __restrict__ W1, const __bf16* __restrict__ W2,
    const float* __restrict__ b0, const float* __restrict__ b1, const float* __restrict__ b2,
    __bf16* __restrict__ O0, __bf16* __restrict__ O1, __bf16* __restrict__ O2) {
  const int z = blockIdx.z;
  const __bf16* A = (z == 0) ? A0 : (z == 1) ? A1 : A2;
  const __bf16* W = (z == 0) ? W0 : (z == 1) ? W1 : W2;
  const float* bias = (z == 0) ? b0 : (z == 1) ? b1 : b2;
  __bf16* OutB = (z == 0) ? O0 : (z == 1) ? O1 : O2;
  const float scale = (z == 0) ? 0.125f * kLog2e : 1.0f;

  const int n0 = blockIdx.x * 128;
  const int m0 = blockIdx.y * 128;
  const int tid = threadIdx.x;
  const int wave = tid >> 6, lane = tid & 63;
  const int g = lane >> 4, qi = lane & 15;
  const int wm = wave >> 1, wn = wave & 1;

  __shared__ __align__(16) __bf16 As[128 * 32];
  __shared__ __align__(16) __bf16 Bs[128 * 32];
  __shared__ __align__(16) __bf16 Ts[64 * 136];  // z==2 transpose bounce

  f32x4 acc[4][4];
#pragma unroll
  for (int i = 0; i < 4; ++i)
#pragma unroll
    for (int jj = 0; jj < 4; ++jj) acc[i][jj] = (f32x4){0.f, 0.f, 0.f, 0.f};

  for (int k0 = 0; k0 < kE; k0 += 32) {
#pragma unroll
    for (int jj = 0; jj < 2; ++jj) {
      const int c = jj * 256 + tid;
      const int r = c >> 2, sl = c & 3;
      gload_lds16(&A[(size_t)(m0 + r) * kE + k0 + sl * 8], &As[c * 8]);
      gload_lds16(&W[(size_t)(n0 + r) * kE + k0 + sl * 8], &Bs[c * 8]);
    }
    __syncthreads();

    bf16x8 af[4], bfr[4];
#pragma unroll
    for (int mi = 0; mi < 4; ++mi)
      af[mi] = *(const bf16x8*)&As[(wm * 64 + mi * 16 + qi) * 32 + g * 8];
#pragma unroll
    for (int nj = 0; nj < 4; ++nj)
      bfr[nj] = *(const bf16x8*)&Bs[(wn * 64 + nj * 16 + qi) * 32 + g * 8];
#pragma unroll
    for (int mi = 0; mi < 4; ++mi)
#pragma unroll
      for (int nj = 0; nj < 4; ++nj)
        acc[mi][nj] = MFMA16(af[mi], bfr[nj], acc[mi][nj]);
    __syncthreads();
  }

  if (z == 2) {
    // transposed epilogue: half = wn-owned 64 columns at a time
    const int bb = m0 >> 11, ss0 = m0 & 2047;
#pragma unroll
    for (int half = 0; half < 2; ++half) {
      __syncthreads();
      if (wn == half) {
#pragma unroll
        for (int nj = 0; nj < 4; ++nj) {
          const int dl = nj * 16 + qi;  // 0..63 within half
          const float bn = bias[n0 + half * 64 + dl];
#pragma unroll
          for (int mi = 0; mi < 4; ++mi) {
            const int srow = wm * 64 + mi * 16 + g * 4;
            bf16x4 o;
#pragma unroll
            for (int r = 0; r < 4; ++r) o[r] = (__bf16)(acc[mi][nj][r] + bn);
            *(bf16x4*)&Ts[dl * 136 + srow] = o;
          }
        }
      }
      __syncthreads();
      // copy out: 64 d-rows x 128 s-cols, coalesced
      const int drow = tid >> 2, sc = (tid & 3) * 32;
      const int head = (n0 + half * 64) >> 6;
      __bf16* dst = OutB + (((size_t)bb * kH + head) * kD + drow) * kS + ss0 + sc;
#pragma unroll
      for (int jj = 0; jj < 4; ++jj) {
        bf16x8 vv = *(const bf16x8*)&Ts[drow * 136 + sc + jj * 8];
        *(bf16x8*)&dst[jj * 8] = vv;
      }
    }
    return;
  }

#pragma unroll
  for (int nj = 0; nj < 4; ++nj) {
    const int ncol = n0 + wn * 64 + nj * 16 + qi;
    const float bn = bias[ncol];
    const int hh = ncol >> 6, dd = ncol & 63;
#pragma unroll
    for (int mi = 0; mi < 4; ++mi) {
#pragma unroll
      for (int r = 0; r < 4; ++r) {
        const int mrow = m0 + wm * 64 + mi * 16 + g * 4 + r;
        const float vv = (acc[mi][nj][r] + bn) * scale;
        const int bb = mrow >> 11, ss = mrow & 2047;
        OutB[((((size_t)bb * kH + hh) * kS + ss) << 6) + dd] = (__bf16)vv;
      }
    }
  }
}

// ---------------------------------------------------------------------------
// Kernel 3: out projection, C = A[4096,1024] @ Wo^T + bo -> f32, 128x64 tile
// ---------------------------------------------------------------------------
__global__ __launch_bounds__(256) void gemm_out64(
    const __bf16* __restrict__ A, const __bf16* __restrict__ W,
    const float* __restrict__ bias, float* __restrict__ OF) {
  const int n0 = blockIdx.x * 64;
  const int m0 = blockIdx.y * 128;
  const int tid = threadIdx.x;
  const int wave = tid >> 6, lane = tid & 63;
  const int g = lane >> 4, qi = lane & 15;
  const int wm = wave >> 1, wn = wave & 1;

  __shared__ __align__(16) __bf16 As[128 * 32];
  __shared__ __align__(16) __bf16 Bs[64 * 32];

  f32x4 acc[4][2];
#pragma unroll
  for (int i = 0; i < 4; ++i)
#pragma unroll
    for (int jj = 0; jj < 2; ++jj) acc[i][jj] = (f32x4){0.f, 0.f, 0.f, 0.f};

  for (int k0 = 0; k0 < kE; k0 += 32) {
#pragma unroll
    for (int jj = 0; jj < 2; ++jj) {
      const int c = jj * 256 + tid;
      const int r = c >> 2, sl = c & 3;
      gload_lds16(&A[(size_t)(m0 + r) * kE + k0 + sl * 8], &As[c * 8]);
    }
    {
      const int r = tid >> 2, sl = tid & 3;
      gload_lds16(&W[(size_t)(n0 + r) * kE + k0 + sl * 8], &Bs[tid * 8]);
    }
    __syncthreads();

    bf16x8 af[4], bfr[2];
#pragma unroll
    for (int mi = 0; mi < 4; ++mi)
      af[mi] = *(const bf16x8*)&As[(wm * 64 + mi * 16 + qi) * 32 + g * 8];
#pragma unroll
    for (int nj = 0; nj < 2; ++nj)
      bfr[nj] = *(const bf16x8*)&Bs[(wn * 32 + nj * 16 + qi) * 32 + g * 8];
#pragma unroll
    for (int mi = 0; mi < 4; ++mi)
#pragma unroll
      for (int nj = 0; nj < 2; ++nj)
        acc[mi][nj] = MFMA16(af[mi], bfr[nj], acc[mi][nj]);
    __syncthreads();
  }

#pragma unroll
  for (int nj = 0; nj < 2; ++nj) {
    const int ncol = n0 + wn * 32 + nj * 16 + qi;
    const float bn = bias[ncol];
#pragma unroll
    for (int mi = 0; mi < 4; ++mi)
#pragma unroll
      for (int r = 0; r < 4; ++r) {
        const int mrow = m0 + wm * 64 + mi * 16 + g * 4 + r;
        OF[(size_t)mrow * kE + ncol] = acc[mi][nj][r] + bn;
      }
  }
}

// ---------------------------------------------------------------------------
// Kernel 4: flash attention. 8 waves/block, 16 q-rows/wave, 128 q-rows/block.
// K/V kv-tiles (64x64) double-buffered in LDS (both-sides XOR swizzle).
// Swapped QK^T; fixed-m exp2 softmax (m==0): masked scores -> -inf -> exp2=0;
// den accumulated per-lane, reduced once after the loop.
// ---------------------------------------------------------------------------
__global__ __launch_bounds__(512, 4) void attn_kernel(
    const __bf16* __restrict__ Qh, const __bf16* __restrict__ Kh,
    const __bf16* __restrict__ Vt, const unsigned long long* __restrict__ mw,
    __bf16* __restrict__ Ob) {
  const int tid = threadIdx.x;
  const int wave = tid >> 6, lane = tid & 63;
  const int g = lane >> 4, qi = lane & 15;
  // XCD swizzle: 512 blocks; xcd = id%8 owns heads xcd*4..xcd*4+3.
  const int id = blockIdx.x;
  const int xcd = id & 7, j = id >> 3;
  const int bh = xcd * 4 + (j >> 4);
  const int qb = j & 15;
  const int b = bh >> 4, h = bh & 15;

  __shared__ __align__(16) __bf16 Ks[2][64 * 64];
  __shared__ __align__(16) __bf16 Vs[2][64 * 64];

  const __bf16* Qp = Qh + (size_t)bh * kS * kD;
  const __bf16* Kp = Kh + (size_t)bh * kS * kD;
  const __bf16* Vp = Vt + (size_t)bh * kD * kS;

  const int q0 = qb * 128 + wave * 16 + qi;
  const unsigned long long* M0 = mw + (size_t)(b * kS + q0) * kMaskWordsPerRow;

  // Q fragments (B-operand); (1/8)*log2e pre-folded into Qh.
  const bf16x8 qf0 = *(const bf16x8*)&Qp[(size_t)q0 * kD + g * 8];
  const bf16x8 qf1 = *(const bf16x8*)&Qp[(size_t)q0 * kD + 32 + g * 8];

  f32x4 acc[4];
#pragma unroll
  for (int f = 0; f < 4; ++f) acc[f] = (f32x4){0.f, 0.f, 0.f, 0.f};
  float den = 0.f;
  const float ninf = __builtin_bit_cast(float, 0xff800000u);

  // stage: 512 threads, 1 K-chunk + 1 V-chunk (16B) each; linear LDS dest,
  // inverse-swizzled global source slot (sl ^ (row&7)).
  const int srow = tid >> 3, ssl = tid & 7;
  const int ssls = ssl ^ (srow & 7);
  auto stage = [&](int buf, int kv0) {
    gload_lds16(&Kp[(size_t)(kv0 + srow) * kD + ssls * 8], &Ks[buf][tid * 8]);
    gload_lds16(&Vp[(size_t)srow * kS + kv0 + ssls * 8], &Vs[buf][tid * 8]);
  };

  stage(0, 0);
  __syncthreads();

  const int sw = qi & 7;
  for (int t = 0; t < 32; ++t) {
    const int cur = t & 1;
    if (t < 31) stage(cur ^ 1, (t + 1) * 64);
    const unsigned long long w = M0[t];
    const unsigned wlo = (unsigned)(w >> (g * 4));
    const unsigned whi = (unsigned)(w >> (32 + g * 4));
    const unsigned wf[4] = {wlo, wlo >> 16, whi, whi >> 16};

    // ---- QK^T (swapped): p[kv 16][q], masked to -inf ----
    float p[16];
    __builtin_amdgcn_s_setprio(1);
#pragma unroll
    for (int f = 0; f < 4; ++f) {
      const int r = f * 16 + qi;
      const bf16x8 k0 = *(const bf16x8*)&Ks[cur][r * 64 + ((g ^ sw) * 8)];
      const bf16x8 k1 = *(const bf16x8*)&Ks[cur][r * 64 + (((4 + g) ^ sw) * 8)];
      f32x4 st = (f32x4){0.f, 0.f, 0.f, 0.f};
      st = MFMA16(k0, qf0, st);
      st = MFMA16(k1, qf1, st);
#pragma unroll
      for (int r4 = 0; r4 < 4; ++r4)
        p[4 * f + r4] = (wf[f] & (1u << r4)) ? st[r4] : ninf;
    }
    __builtin_amdgcn_s_setprio(0);

    // ---- exp2 (fixed m=0; masked -> exp2(-inf)=0), per-lane den ----
#pragma unroll
    for (int i = 0; i < 16; ++i) {
      p[i] = EXP2(p[i]);
      den += p[i];
    }

    // ---- P -> bf16 PV B-fragments via cross-lane shuffle, then PV ----
    unsigned pk[4][2];
#pragma unroll
    for (int f = 0; f < 4; ++f) {
      pk[f][0] = pack_bf16x2(p[4 * f + 0], p[4 * f + 1]);
      pk[f][1] = pack_bf16x2(p[4 * f + 2], p[4 * f + 3]);
    }
#pragma unroll
    for (int c = 0; c < 2; ++c) {
      unsigned bw[4];
#pragma unroll
      for (int t4 = 0; t4 < 4; ++t4) {
        const int src = qi + 16 * ((t4 >> 1) + 2 * (g & 1));
        const int vA = __shfl((int)pk[2 * c + 0][t4 & 1], src);
        const int vB = __shfl((int)pk[2 * c + 1][t4 & 1], src);
        bw[t4] = (g >= 2) ? (unsigned)vB : (unsigned)vA;
      }
      const u32x4 tmp = {bw[0], bw[1], bw[2], bw[3]};
      const bf16x8 pb = __builtin_bit_cast(bf16x8, tmp);
      __builtin_amdgcn_s_setprio(1);
#pragma unroll
      for (int f = 0; f < 4; ++f) {
        const int r = f * 16 + qi;
        const bf16x8 vfr =
            *(const bf16x8*)&Vs[cur][r * 64 + (((c * 4 + g) ^ sw) * 8)];
        acc[f] = MFMA16(vfr, pb, acc[f]);
      }
      __builtin_amdgcn_s_setprio(0);
    }
    __syncthreads();
  }

  den += __shfl_xor(den, 16);
  den += __shfl_xor(den, 32);
  const float rinv = 1.0f / den;
  __bf16* Op = Ob + (size_t)(b * kS + q0) * kE + h * kD;
#pragma unroll
  for (int f = 0; f < 4; ++f) {
    ushort4 o;
    o.x = __builtin_bit_cast(unsigned short, (__bf16)(acc[f][0] * rinv));
    o.y = __builtin_bit_cast(unsigned short, (__bf16)(acc[f][1] * rinv));
    o.z = __builtin_bit_cast(unsigned short, (__bf16)(acc[f][2] * rinv));
    o.w = __builtin_bit_cast(unsigned short, (__bf16)(acc[f][3] * rinv));
    *(ushort4*)&Op[f * 16 + g * 4] = o;
  }
}

// ---------------------------------------------------------------------------
extern "C" void kernel_launch(void* const* d_in, const int* in_sizes, int n_in,
                              void* d_out, int out_size, void* d_ws, size_t ws_size,
                              hipStream_t stream) {
  (void)in_sizes; (void)n_in; (void)out_size; (void)ws_size;
  const float* q  = (const float*)d_in[0];
  const float* k  = (const float*)d_in[1];
  const float* v  = (const float*)d_in[2];
  const int*   mask = (const int*)d_in[3];
  const float* Wq = (const float*)d_in[4];
  const float* bq = (const float*)d_in[5];
  const float* Wk = (const float*)d_in[6];
  const float* bk = (const float*)d_in[7];
  const float* Wv = (const float*)d_in[8];
  const float* bv = (const float*)d_in[9];
  const float* Wo = (const float*)d_in[10];
  const float* bo = (const float*)d_in[11];

  char* ws = (char*)d_ws;
  const size_t MB = 1024 * 1024;
  __bf16* qb  = (__bf16*)(ws + 0 * MB);    // 8MB  [4096,1024]
  __bf16* kb  = (__bf16*)(ws + 8 * MB);    // 8MB
  __bf16* vb  = (__bf16*)(ws + 16 * MB);   // 8MB
  __bf16* wqb = (__bf16*)(ws + 24 * MB);   // 2MB
  __bf16* wkb = (__bf16*)(ws + 26 * MB);   // 2MB
  __bf16* wvb = (__bf16*)(ws + 28 * MB);   // 2MB
  __bf16* wob = (__bf16*)(ws + 30 * MB);   // 2MB
  __bf16* Qh  = (__bf16*)(ws + 32 * MB);   // 8MB [B,H,S,D]
  __bf16* Kh  = (__bf16*)(ws + 40 * MB);   // 8MB [B,H,S,D]
  __bf16* Vt  = (__bf16*)(ws + 48 * MB);   // 8MB [B,H,D,S]
  unsigned long long* mwords = (unsigned long long*)(ws + 56 * MB);  // 1MB
  __bf16* Ob = qb;   // qb dead after QKV GEMM

  cvt_pack_kernel<<<dim3(256, 8), 256, 0, stream>>>(
      q, k, v, Wq, Wk, Wv, Wo, mask, qb, kb, vb, wqb, wkb, wvb, wob, mwords);
  gemm_bt<<<dim3(8, 32, 3), 256, 0, stream>>>(qb, kb, vb, wqb, wkb, wvb,
                                              bq, bk, bv, Qh, Kh, Vt);
  attn_kernel<<<512, 512, 0, stream>>>(Qh, Kh, Vt, mwords, Ob);
  gemm_out64<<<dim3(16, 32), 256, 0, stream>>>(Ob, wob, bo, (float*)d_out);
}

// Round 5
// 285.948 us; speedup vs baseline: 1.1477x; 1.1477x over previous
//
#include <hip/hip_runtime.h>
#include <hip/hip_bf16.h>
#include <stdint.h>

// ---------------------------------------------------------------------------
// MHA forward, B=2 S=2048 E=1024 H=16 D=64, fp32 in/out, bf16 MFMA internally.
// cvt+pack (flat balanced grid) -> QKV proj GEMM (z=3; z==2 writes V^T) ->
// flash attention (BK=128 LDS dbuf K/V, both-sides swizzle, swapped QK^T,
// fixed-m exp2 softmax) -> out proj (128x64 tiles).
// ---------------------------------------------------------------------------

typedef __bf16 bf16x8 __attribute__((ext_vector_type(8)));
typedef __bf16 bf16x4 __attribute__((ext_vector_type(4)));
typedef float  f32x4  __attribute__((ext_vector_type(4)));
typedef unsigned int u32x4 __attribute__((ext_vector_type(4)));

#define MFMA16(a, b, c) __builtin_amdgcn_mfma_f32_16x16x32_bf16((a), (b), (c), 0, 0, 0)

#if __has_builtin(__builtin_amdgcn_exp2f)
#define EXP2(x) __builtin_amdgcn_exp2f(x)
#else
#define EXP2(x) exp2f(x)
#endif

static constexpr int kB = 2, kS = 2048, kE = 1024, kH = 16, kD = 64;
static constexpr int kM = kB * kS;                // 4096 rows
static constexpr int kMaskWordsPerRow = kS / 64;  // 32
static constexpr float kLog2e = 1.4426950408889634f;

// ---- async global->LDS (16B per lane, wave-uniform LDS base) --------------
__device__ __forceinline__ void gload_lds16(const void* g, void* l) {
  __builtin_amdgcn_global_load_lds(
      (const __attribute__((address_space(1))) unsigned int*)g,
      (__attribute__((address_space(3))) unsigned int*)l, 16, 0, 0);
}

__device__ __forceinline__ unsigned pack_bf16x2(float a, float b) {
  unsigned short lo = __builtin_bit_cast(unsigned short, (__bf16)a);
  unsigned short hi = __builtin_bit_cast(unsigned short, (__bf16)b);
  return (unsigned)lo | ((unsigned)hi << 16);
}

// ---------------------------------------------------------------------------
// Kernel 1: flat balanced grid.
// blocks [0,960): f32->bf16 of q,k,v (320 each, 2xfloat4 per iter)
// blocks [960,1216): weights Wq,Wk,Wv,Wo (64 each)
// blocks [1216,1664): mask bit-pack, 4 ballot words per wave-iter (MLP)
// ---------------------------------------------------------------------------
static constexpr int kCvtBlocks = 1664;

__global__ __launch_bounds__(256) void cvt_pack_kernel(
    const float* __restrict__ q, const float* __restrict__ k, const float* __restrict__ v,
    const float* __restrict__ wq, const float* __restrict__ wk,
    const float* __restrict__ wv, const float* __restrict__ wo,
    const int* __restrict__ mask,
    __bf16* __restrict__ qb, __bf16* __restrict__ kb, __bf16* __restrict__ vb,
    __bf16* __restrict__ wqb, __bf16* __restrict__ wkb,
    __bf16* __restrict__ wvb, __bf16* __restrict__ wob,
    unsigned long long* __restrict__ mw) {
  const int bid = blockIdx.x;
  if (bid < 1216) {
    const float* src; __bf16* dst; int n8, t0, stride;
    if (bid < 960) {
      const int seg = bid / 320, sb = bid - seg * 320;
      src = (seg == 0) ? q : (seg == 1) ? k : v;
      dst = (seg == 0) ? qb : (seg == 1) ? kb : vb;
      n8 = (kM * kE) >> 3;            // 524288 groups of 8
      t0 = sb * 256 + threadIdx.x;
      stride = 320 * 256;
    } else {
      const int wseg = (bid - 960) >> 6, sb = (bid - 960) & 63;
      src = (wseg == 0) ? wq : (wseg == 1) ? wk : (wseg == 2) ? wv : wo;
      dst = (wseg == 0) ? wqb : (wseg == 1) ? wkb : (wseg == 2) ? wvb : wob;
      n8 = (kE * kE) >> 3;            // 131072 groups of 8
      t0 = sb * 256 + threadIdx.x;
      stride = 64 * 256;
    }
    for (int i = t0; i < n8; i += stride) {
      float4 f0 = ((const float4*)src)[2 * i];
      float4 f1 = ((const float4*)src)[2 * i + 1];
      bf16x8 o = {(__bf16)f0.x, (__bf16)f0.y, (__bf16)f0.z, (__bf16)f0.w,
                  (__bf16)f1.x, (__bf16)f1.y, (__bf16)f1.z, (__bf16)f1.w};
      ((bf16x8*)dst)[i] = o;
    }
    return;
  }
  // mask pack: 448 blocks * 4 waves; each wave-iter handles 4 words.
  const int lane = threadIdx.x & 63;
  const int wid = ((bid - 1216) * 4 + (threadIdx.x >> 6));  // 0..1791
  const int nwords = kB * kS * kMaskWordsPerRow;            // 131072
  const int stride4 = 1792 * 4;
  for (int w = wid * 4; w < nwords; w += stride4) {
    const int v0 = mask[(size_t)(w + 0) * 64 + lane];
    const int v1 = mask[(size_t)(w + 1) * 64 + lane];
    const int v2 = mask[(size_t)(w + 2) * 64 + lane];
    const int v3 = mask[(size_t)(w + 3) * 64 + lane];
    const unsigned long long b0 = __ballot(v0 != 0);
    const unsigned long long b1 = __ballot(v1 != 0);
    const unsigned long long b2 = __ballot(v2 != 0);
    const unsigned long long b3 = __ballot(v3 != 0);
    if (lane == 0) {
      ulonglong2 lo = {b0, b1}, hi = {b2, b3};
      *(ulonglong2*)&mw[w] = lo;
      *(ulonglong2*)&mw[w + 2] = hi;
    }
  }
}

// ---------------------------------------------------------------------------
// Kernel 2: C = A[4096,1024] @ W^T + bias (NT, bf16 MFMA), 128x128 tile.
// z=0: -> Qh [B,H,S,D] scaled by (1/8)*log2e; z=1: -> Kh [B,H,S,D];
// z=2: -> Vt [B,H,D,S] via LDS-bounced transposed epilogue.
// ---------------------------------------------------------------------------
__global__ __launch_bounds__(256) void gemm_bt(
    const __bf16* __restrict__ A0, const __bf16* __restrict__ A1, const __bf16* __restrict__ A2,
    const __bf16* __restrict__ W0, const __bf16* __restrict__ W1, const __bf16* __restrict__ W2,
    const float* __restrict__ b0, const float* __restrict__ b1, const float* __restrict__ b2,
    __bf16* __restrict__ O0, __bf16* __restrict__ O1, __bf16* __restrict__ O2) {
  const int z = blockIdx.z;
  const __bf16* A = (z == 0) ? A0 : (z == 1) ? A1 : A2;
  const __bf16* W = (z == 0) ? W0 : (z == 1) ? W1 : W2;
  const float* bias = (z == 0) ? b0 : (z == 1) ? b1 : b2;
  __bf16* OutB = (z == 0) ? O0 : (z == 1) ? O1 : O2;
  const float scale = (z == 0) ? 0.125f * kLog2e : 1.0f;

  const int n0 = blockIdx.x * 128;
  const int m0 = blockIdx.y * 128;
  const int tid = threadIdx.x;
  const int wave = tid >> 6, lane = tid & 63;
  const int g = lane >> 4, qi = lane & 15;
  const int wm = wave >> 1, wn = wave & 1;

  __shared__ __align__(16) __bf16 As[128 * 32];
  __shared__ __align__(16) __bf16 Bs[128 * 32];
  __shared__ __align__(16) __bf16 Ts[64 * 136];  // z==2 transpose bounce

  f32x4 acc[4][4];
#pragma unroll
  for (int i = 0; i < 4; ++i)
#pragma unroll
    for (int jj = 0; jj < 4; ++jj) acc[i][jj] = (f32x4){0.f, 0.f, 0.f, 0.f};

  for (int k0 = 0; k0 < kE; k0 += 32) {
#pragma unroll
    for (int jj = 0; jj < 2; ++jj) {
      const int c = jj * 256 + tid;
      const int r = c >> 2, sl = c & 3;
      gload_lds16(&A[(size_t)(m0 + r) * kE + k0 + sl * 8], &As[c * 8]);
      gload_lds16(&W[(size_t)(n0 + r) * kE + k0 + sl * 8], &Bs[c * 8]);
    }
    __syncthreads();

    bf16x8 af[4], bfr[4];
#pragma unroll
    for (int mi = 0; mi < 4; ++mi)
      af[mi] = *(const bf16x8*)&As[(wm * 64 + mi * 16 + qi) * 32 + g * 8];
#pragma unroll
    for (int nj = 0; nj < 4; ++nj)
      bfr[nj] = *(const bf16x8*)&Bs[(wn * 64 + nj * 16 + qi) * 32 + g * 8];
#pragma unroll
    for (int mi = 0; mi < 4; ++mi)
#pragma unroll
      for (int nj = 0; nj < 4; ++nj)
        acc[mi][nj] = MFMA16(af[mi], bfr[nj], acc[mi][nj]);
    __syncthreads();
  }

  if (z == 2) {
    const int bb = m0 >> 11, ss0 = m0 & 2047;
#pragma unroll
    for (int half = 0; half < 2; ++half) {
      __syncthreads();
      if (wn == half) {
#pragma unroll
        for (int nj = 0; nj < 4; ++nj) {
          const int dl = nj * 16 + qi;  // 0..63 within half
          const float bn = bias[n0 + half * 64 + dl];
#pragma unroll
          for (int mi = 0; mi < 4; ++mi) {
            const int srow = wm * 64 + mi * 16 + g * 4;
            bf16x4 o;
#pragma unroll
            for (int r = 0; r < 4; ++r) o[r] = (__bf16)(acc[mi][nj][r] + bn);
            *(bf16x4*)&Ts[dl * 136 + srow] = o;
          }
        }
      }
      __syncthreads();
      const int drow = tid >> 2, sc = (tid & 3) * 32;
      const int head = (n0 + half * 64) >> 6;
      __bf16* dst = OutB + (((size_t)bb * kH + head) * kD + drow) * kS + ss0 + sc;
#pragma unroll
      for (int jj = 0; jj < 4; ++jj) {
        bf16x8 vv = *(const bf16x8*)&Ts[drow * 136 + sc + jj * 8];
        *(bf16x8*)&dst[jj * 8] = vv;
      }
    }
    return;
  }

#pragma unroll
  for (int nj = 0; nj < 4; ++nj) {
    const int ncol = n0 + wn * 64 + nj * 16 + qi;
    const float bn = bias[ncol];
    const int hh = ncol >> 6, dd = ncol & 63;
#pragma unroll
    for (int mi = 0; mi < 4; ++mi) {
#pragma unroll
      for (int r = 0; r < 4; ++r) {
        const int mrow = m0 + wm * 64 + mi * 16 + g * 4 + r;
        const float vv = (acc[mi][nj][r] + bn) * scale;
        const int bb = mrow >> 11, ss = mrow & 2047;
        OutB[((((size_t)bb * kH + hh) * kS + ss) << 6) + dd] = (__bf16)vv;
      }
    }
  }
}

// ---------------------------------------------------------------------------
// Kernel 3: out projection, C = A[4096,1024] @ Wo^T + bo -> f32, 128x64 tile
// ---------------------------------------------------------------------------
__global__ __launch_bounds__(256) void gemm_out64(
    const __bf16* __restrict__ A, const __bf16* __restrict__ W,
    const float* __restrict__ bias, float* __restrict__ OF) {
  const int n0 = blockIdx.x * 64;
  const int m0 = blockIdx.y * 128;
  const int tid = threadIdx.x;
  const int wave = tid >> 6, lane = tid & 63;
  const int g = lane >> 4, qi = lane & 15;
  const int wm = wave >> 1, wn = wave & 1;

  __shared__ __align__(16) __bf16 As[128 * 32];
  __shared__ __align__(16) __bf16 Bs[64 * 32];

  f32x4 acc[4][2];
#pragma unroll
  for (int i = 0; i < 4; ++i)
#pragma unroll
    for (int jj = 0; jj < 2; ++jj) acc[i][jj] = (f32x4){0.f, 0.f, 0.f, 0.f};

  for (int k0 = 0; k0 < kE; k0 += 32) {
#pragma unroll
    for (int jj = 0; jj < 2; ++jj) {
      const int c = jj * 256 + tid;
      const int r = c >> 2, sl = c & 3;
      gload_lds16(&A[(size_t)(m0 + r) * kE + k0 + sl * 8], &As[c * 8]);
    }
    {
      const int r = tid >> 2, sl = tid & 3;
      gload_lds16(&W[(size_t)(n0 + r) * kE + k0 + sl * 8], &Bs[tid * 8]);
    }
    __syncthreads();

    bf16x8 af[4], bfr[2];
#pragma unroll
    for (int mi = 0; mi < 4; ++mi)
      af[mi] = *(const bf16x8*)&As[(wm * 64 + mi * 16 + qi) * 32 + g * 8];
#pragma unroll
    for (int nj = 0; nj < 2; ++nj)
      bfr[nj] = *(const bf16x8*)&Bs[(wn * 32 + nj * 16 + qi) * 32 + g * 8];
#pragma unroll
    for (int mi = 0; mi < 4; ++mi)
#pragma unroll
      for (int nj = 0; nj < 2; ++nj)
        acc[mi][nj] = MFMA16(af[mi], bfr[nj], acc[mi][nj]);
    __syncthreads();
  }

#pragma unroll
  for (int nj = 0; nj < 2; ++nj) {
    const int ncol = n0 + wn * 32 + nj * 16 + qi;
    const float bn = bias[ncol];
#pragma unroll
    for (int mi = 0; mi < 4; ++mi)
#pragma unroll
      for (int r = 0; r < 4; ++r) {
        const int mrow = m0 + wm * 64 + mi * 16 + g * 4 + r;
        OF[(size_t)mrow * kE + ncol] = acc[mi][nj][r] + bn;
      }
  }
}

// ---------------------------------------------------------------------------
// Kernel 4: flash attention. 8 waves/block, 16 q-rows/wave, 128 q-rows/block.
// K/V staged in BK=128 double-buffered LDS tiles (both-sides XOR swizzle) ->
// one vmcnt-drain barrier per 128 kv instead of per 64.
// Swapped QK^T; fixed-m exp2 softmax (masked -> -inf -> exp2=0); den
// accumulated per-lane, reduced once after the loop.
// ---------------------------------------------------------------------------
__global__ __launch_bounds__(512, 4) void attn_kernel(
    const __bf16* __restrict__ Qh, const __bf16* __restrict__ Kh,
    const __bf16* __restrict__ Vt, const unsigned long long* __restrict__ mw,
    __bf16* __restrict__ Ob) {
  const int tid = threadIdx.x;
  const int wave = tid >> 6, lane = tid & 63;
  const int g = lane >> 4, qi = lane & 15;
  // XCD swizzle: 512 blocks; xcd = id%8 owns heads xcd*4..xcd*4+3.
  const int id = blockIdx.x;
  const int xcd = id & 7, j = id >> 3;
  const int bh = xcd * 4 + (j >> 4);
  const int qb = j & 15;
  const int b = bh >> 4, h = bh & 15;

  __shared__ __align__(16) __bf16 Ks[2][128 * 64];  // [kv 128][d 64]
  __shared__ __align__(16) __bf16 Vs[2][64 * 128];  // [d 64][kv 128]

  const __bf16* Qp = Qh + (size_t)bh * kS * kD;
  const __bf16* Kp = Kh + (size_t)bh * kS * kD;
  const __bf16* Vp = Vt + (size_t)bh * kD * kS;

  const int q0 = qb * 128 + wave * 16 + qi;
  const unsigned long long* M0 = mw + (size_t)(b * kS + q0) * kMaskWordsPerRow;

  // Q fragments (B-operand); (1/8)*log2e pre-folded into Qh.
  const bf16x8 qf0 = *(const bf16x8*)&Qp[(size_t)q0 * kD + g * 8];
  const bf16x8 qf1 = *(const bf16x8*)&Qp[(size_t)q0 * kD + 32 + g * 8];

  f32x4 acc[4];
#pragma unroll
  for (int f = 0; f < 4; ++f) acc[f] = (f32x4){0.f, 0.f, 0.f, 0.f};
  float den = 0.f;
  const float ninf = __builtin_bit_cast(float, 0xff800000u);

  // stage one BK=128 kv-tile: K 128x64 (8 slots/row), V 64x128 (16 slots/row).
  // linear LDS dest chunk c; global source slot = sl ^ (row&7) (involution).
  auto stage = [&](int buf, int kv0) {
#pragma unroll
    for (int jj = 0; jj < 2; ++jj) {
      const int c = jj * 512 + tid;
      const int kr = c >> 3, ksl = c & 7;
      gload_lds16(&Kp[(size_t)(kv0 + kr) * kD + (ksl ^ (kr & 7)) * 8],
                  &Ks[buf][c * 8]);
      const int vr = c >> 4, vsl = c & 15;
      gload_lds16(&Vp[(size_t)vr * kS + kv0 + (vsl ^ (vr & 7)) * 8],
                  &Vs[buf][c * 8]);
    }
  };

  stage(0, 0);
  __syncthreads();

  const int sw = qi & 7;
  for (int t = 0; t < 16; ++t) {
    const int cur = t & 1;
    if (t < 15) stage(cur ^ 1, (t + 1) * 128);
    const ulonglong2 wpair = *(const ulonglong2*)&M0[2 * t];
#pragma unroll
    for (int u = 0; u < 2; ++u) {
      const unsigned long long w = u ? wpair.y : wpair.x;
      const unsigned wlo = (unsigned)(w >> (g * 4));
      const unsigned whi = (unsigned)(w >> (32 + g * 4));
      const unsigned wf[4] = {wlo, wlo >> 16, whi, whi >> 16};

      // ---- QK^T (swapped): p[kv 16][q], masked to -inf ----
      float p[16];
      __builtin_amdgcn_s_setprio(1);
#pragma unroll
      for (int f = 0; f < 4; ++f) {
        const int r = u * 64 + f * 16 + qi;
        const bf16x8 k0 = *(const bf16x8*)&Ks[cur][r * 64 + ((g ^ sw) * 8)];
        const bf16x8 k1 = *(const bf16x8*)&Ks[cur][r * 64 + (((4 + g) ^ sw) * 8)];
        f32x4 st = (f32x4){0.f, 0.f, 0.f, 0.f};
        st = MFMA16(k0, qf0, st);
        st = MFMA16(k1, qf1, st);
#pragma unroll
        for (int r4 = 0; r4 < 4; ++r4)
          p[4 * f + r4] = (wf[f] & (1u << r4)) ? st[r4] : ninf;
      }
      __builtin_amdgcn_s_setprio(0);

      // ---- exp2 (fixed m=0; masked -> exp2(-inf)=0), per-lane den ----
#pragma unroll
      for (int i = 0; i < 16; ++i) {
        p[i] = EXP2(p[i]);
        den += p[i];
      }

      // ---- P -> bf16 PV B-fragments via cross-lane shuffle, then PV ----
      unsigned pk[4][2];
#pragma unroll
      for (int f = 0; f < 4; ++f) {
        pk[f][0] = pack_bf16x2(p[4 * f + 0], p[4 * f + 1]);
        pk[f][1] = pack_bf16x2(p[4 * f + 2], p[4 * f + 3]);
      }
#pragma unroll
      for (int c = 0; c < 2; ++c) {
        unsigned bw[4];
#pragma unroll
        for (int t4 = 0; t4 < 4; ++t4) {
          const int src = qi + 16 * ((t4 >> 1) + 2 * (g & 1));
          const int vA = __shfl((int)pk[2 * c + 0][t4 & 1], src);
          const int vB = __shfl((int)pk[2 * c + 1][t4 & 1], src);
          bw[t4] = (g >= 2) ? (unsigned)vB : (unsigned)vA;
        }
        const u32x4 tmp = {bw[0], bw[1], bw[2], bw[3]};
        const bf16x8 pb = __builtin_bit_cast(bf16x8, tmp);
        __builtin_amdgcn_s_setprio(1);
#pragma unroll
        for (int f = 0; f < 4; ++f) {
          const int rd = f * 16 + qi;
          const int slot = (u * 8 + c * 4 + g) ^ sw;
          const bf16x8 vfr = *(const bf16x8*)&Vs[cur][rd * 128 + slot * 8];
          acc[f] = MFMA16(vfr, pb, acc[f]);
        }
        __builtin_amdgcn_s_setprio(0);
      }
    }
    __syncthreads();
  }

  den += __shfl_xor(den, 16);
  den += __shfl_xor(den, 32);
  const float rinv = 1.0f / den;
  __bf16* Op = Ob + (size_t)(b * kS + q0) * kE + h * kD;
#pragma unroll
  for (int f = 0; f < 4; ++f) {
    ushort4 o;
    o.x = __builtin_bit_cast(unsigned short, (__bf16)(acc[f][0] * rinv));
    o.y = __builtin_bit_cast(unsigned short, (__bf16)(acc[f][1] * rinv));
    o.z = __builtin_bit_cast(unsigned short, (__bf16)(acc[f][2] * rinv));
    o.w = __builtin_bit_cast(unsigned short, (__bf16)(acc[f][3] * rinv));
    *(ushort4*)&Op[f * 16 + g * 4] = o;
  }
}

// ---------------------------------------------------------------------------
extern "C" void kernel_launch(void* const* d_in, const int* in_sizes, int n_in,
                              void* d_out, int out_size, void* d_ws, size_t ws_size,
                              hipStream_t stream) {
  (void)in_sizes; (void)n_in; (void)out_size; (void)ws_size;
  const float* q  = (const float*)d_in[0];
  const float* k  = (const float*)d_in[1];
  const float* v  = (const float*)d_in[2];
  const int*   mask = (const int*)d_in[3];
  const float* Wq = (const float*)d_in[4];
  const float* bq = (const float*)d_in[5];
  const float* Wk = (const float*)d_in[6];
  const float* bk = (const float*)d_in[7];
  const float* Wv = (const float*)d_in[8];
  const float* bv = (const float*)d_in[9];
  const float* Wo = (const float*)d_in[10];
  const float* bo = (const float*)d_in[11];

  char* ws = (char*)d_ws;
  const size_t MB = 1024 * 1024;
  __bf16* qb  = (__bf16*)(ws + 0 * MB);    // 8MB  [4096,1024]
  __bf16* kb  = (__bf16*)(ws + 8 * MB);    // 8MB
  __bf16* vb  = (__bf16*)(ws + 16 * MB);   // 8MB
  __bf16* wqb = (__bf16*)(ws + 24 * MB);   // 2MB
  __bf16* wkb = (__bf16*)(ws + 26 * MB);   // 2MB
  __bf16* wvb = (__bf16*)(ws + 28 * MB);   // 2MB
  __bf16* wob = (__bf16*)(ws + 30 * MB);   // 2MB
  __bf16* Qh  = (__bf16*)(ws + 32 * MB);   // 8MB [B,H,S,D]
  __bf16* Kh  = (__bf16*)(ws + 40 * MB);   // 8MB [B,H,S,D]
  __bf16* Vt  = (__bf16*)(ws + 48 * MB);   // 8MB [B,H,D,S]
  unsigned long long* mwords = (unsigned long long*)(ws + 56 * MB);  // 1MB
  __bf16* Ob = qb;   // qb dead after QKV GEMM

  cvt_pack_kernel<<<kCvtBlocks, 256, 0, stream>>>(
      q, k, v, Wq, Wk, Wv, Wo, mask, qb, kb, vb, wqb, wkb, wvb, wob, mwords);
  gemm_bt<<<dim3(8, 32, 3), 256, 0, stream>>>(qb, kb, vb, wqb, wkb, wvb,
                                              bq, bk, bv, Qh, Kh, Vt);
  attn_kernel<<<512, 512, 0, stream>>>(Qh, Kh, Vt, mwords, Ob);
  gemm_out64<<<dim3(16, 32), 256, 0, stream>>>(Ob, wob, bo, (float*)d_out);
}

// Round 7
// 277.933 us; speedup vs baseline: 1.1807x; 1.0288x over previous
//
#include <hip/hip_runtime.h>
#include <hip/hip_bf16.h>
#include <stdint.h>

// ---------------------------------------------------------------------------
// MHA forward, B=2 S=2048 E=1024 H=16 D=64, fp32 in/out, bf16 MFMA internally.
// cvt+pack (flat balanced grid) -> QKV proj GEMM (z=3; z==2 writes V^T;
// coalesced LDS-bounced epilogues) -> flash attention (4 waves x 32 q-rows,
// BK=64 LDS dbuf, imm-offset swizzled reads, fixed-m exp2 softmax, den via
// ones-MFMA) -> out proj (128x64 tiles).
// ---------------------------------------------------------------------------

typedef __bf16 bf16x8 __attribute__((ext_vector_type(8)));
typedef __bf16 bf16x4 __attribute__((ext_vector_type(4)));
typedef float  f32x4  __attribute__((ext_vector_type(4)));
typedef unsigned int u32x4 __attribute__((ext_vector_type(4)));

#define MFMA16(a, b, c) __builtin_amdgcn_mfma_f32_16x16x32_bf16((a), (b), (c), 0, 0, 0)

#if __has_builtin(__builtin_amdgcn_exp2f)
#define EXP2(x) __builtin_amdgcn_exp2f(x)
#else
#define EXP2(x) exp2f(x)
#endif

static constexpr int kB = 2, kS = 2048, kE = 1024, kH = 16, kD = 64;
static constexpr int kM = kB * kS;                // 4096 rows
static constexpr int kMaskWordsPerRow = kS / 64;  // 32
static constexpr float kLog2e = 1.4426950408889634f;

// ---- async global->LDS (16B per lane, wave-uniform LDS base) --------------
__device__ __forceinline__ void gload_lds16(const void* g, void* l) {
  __builtin_amdgcn_global_load_lds(
      (const __attribute__((address_space(1))) unsigned int*)g,
      (__attribute__((address_space(3))) unsigned int*)l, 16, 0, 0);
}

__device__ __forceinline__ unsigned pack_bf16x2(float a, float b) {
  unsigned short lo = __builtin_bit_cast(unsigned short, (__bf16)a);
  unsigned short hi = __builtin_bit_cast(unsigned short, (__bf16)b);
  return (unsigned)lo | ((unsigned)hi << 16);
}

// ---------------------------------------------------------------------------
// Kernel 1: flat balanced grid.
// blocks [0,960): f32->bf16 of q,k,v (320 each, 2xfloat4 per iter)
// blocks [960,1216): weights Wq,Wk,Wv,Wo (64 each)
// blocks [1216,1664): mask bit-pack, 4 ballot words per wave-iter (MLP)
// ---------------------------------------------------------------------------
static constexpr int kCvtBlocks = 1664;

__global__ __launch_bounds__(256) void cvt_pack_kernel(
    const float* __restrict__ q, const float* __restrict__ k, const float* __restrict__ v,
    const float* __restrict__ wq, const float* __restrict__ wk,
    const float* __restrict__ wv, const float* __restrict__ wo,
    const int* __restrict__ mask,
    __bf16* __restrict__ qb, __bf16* __restrict__ kb, __bf16* __restrict__ vb,
    __bf16* __restrict__ wqb, __bf16* __restrict__ wkb,
    __bf16* __restrict__ wvb, __bf16* __restrict__ wob,
    unsigned long long* __restrict__ mw) {
  const int bid = blockIdx.x;
  if (bid < 1216) {
    const float* src; __bf16* dst; int n8, t0, stride;
    if (bid < 960) {
      const int seg = bid / 320, sb = bid - seg * 320;
      src = (seg == 0) ? q : (seg == 1) ? k : v;
      dst = (seg == 0) ? qb : (seg == 1) ? kb : vb;
      n8 = (kM * kE) >> 3;
      t0 = sb * 256 + threadIdx.x;
      stride = 320 * 256;
    } else {
      const int wseg = (bid - 960) >> 6, sb = (bid - 960) & 63;
      src = (wseg == 0) ? wq : (wseg == 1) ? wk : (wseg == 2) ? wv : wo;
      dst = (wseg == 0) ? wqb : (wseg == 1) ? wkb : (wseg == 2) ? wvb : wob;
      n8 = (kE * kE) >> 3;
      t0 = sb * 256 + threadIdx.x;
      stride = 64 * 256;
    }
    for (int i = t0; i < n8; i += stride) {
      float4 f0 = ((const float4*)src)[2 * i];
      float4 f1 = ((const float4*)src)[2 * i + 1];
      bf16x8 o = {(__bf16)f0.x, (__bf16)f0.y, (__bf16)f0.z, (__bf16)f0.w,
                  (__bf16)f1.x, (__bf16)f1.y, (__bf16)f1.z, (__bf16)f1.w};
      ((bf16x8*)dst)[i] = o;
    }
    return;
  }
  const int lane = threadIdx.x & 63;
  const int wid = ((bid - 1216) * 4 + (threadIdx.x >> 6));
  const int nwords = kB * kS * kMaskWordsPerRow;  // 131072
  const int stride4 = 1792 * 4;
  for (int w = wid * 4; w < nwords; w += stride4) {
    const int v0 = mask[(size_t)(w + 0) * 64 + lane];
    const int v1 = mask[(size_t)(w + 1) * 64 + lane];
    const int v2 = mask[(size_t)(w + 2) * 64 + lane];
    const int v3 = mask[(size_t)(w + 3) * 64 + lane];
    const unsigned long long b0 = __ballot(v0 != 0);
    const unsigned long long b1 = __ballot(v1 != 0);
    const unsigned long long b2 = __ballot(v2 != 0);
    const unsigned long long b3 = __ballot(v3 != 0);
    if (lane == 0) {
      ulonglong2 lo = {b0, b1}, hi = {b2, b3};
      *(ulonglong2*)&mw[w] = lo;
      *(ulonglong2*)&mw[w + 2] = hi;
    }
  }
}

// ---------------------------------------------------------------------------
// Kernel 2: C = A[4096,1024] @ W^T + bias (NT, bf16 MFMA), 128x128 tile.
// z=0: -> Qh [B,H,S,D] scaled by (1/8)*log2e; z=1: -> Kh [B,H,S,D];
// z=2: -> Vt [B,H,D,S]. All epilogues bounce through LDS for coalesced stores.
// ---------------------------------------------------------------------------
__global__ __launch_bounds__(256) void gemm_bt(
    const __bf16* __restrict__ A0, const __bf16* __restrict__ A1, const __bf16* __restrict__ A2,
    const __bf16* __restrict__ W0, const __bf16* __restrict__ W1, const __bf16* __restrict__ W2,
    const float* __restrict__ b0, const float* __restrict__ b1, const float* __restrict__ b2,
    __bf16* __restrict__ O0, __bf16* __restrict__ O1, __bf16* __restrict__ O2) {
  const int z = blockIdx.z;
  const __bf16* A = (z == 0) ? A0 : (z == 1) ? A1 : A2;
  const __bf16* W = (z == 0) ? W0 : (z == 1) ? W1 : W2;
  const float* bias = (z == 0) ? b0 : (z == 1) ? b1 : b2;
  __bf16* OutB = (z == 0) ? O0 : (z == 1) ? O1 : O2;
  const float scale = (z == 0) ? 0.125f * kLog2e : 1.0f;

  const int n0 = blockIdx.x * 128;
  const int m0 = blockIdx.y * 128;
  const int tid = threadIdx.x;
  const int wave = tid >> 6, lane = tid & 63;
  const int g = lane >> 4, qi = lane & 15;
  const int wm = wave >> 1, wn = wave & 1;

  __shared__ __align__(16) __bf16 As[128 * 32];
  __shared__ __align__(16) __bf16 Bs[128 * 32];
  __shared__ __align__(16) __bf16 Ts[128 * 72];  // epilogue bounce (both modes)

  f32x4 acc[4][4];
#pragma unroll
  for (int i = 0; i < 4; ++i)
#pragma unroll
    for (int jj = 0; jj < 4; ++jj) acc[i][jj] = (f32x4){0.f, 0.f, 0.f, 0.f};

  for (int k0 = 0; k0 < kE; k0 += 32) {
#pragma unroll
    for (int jj = 0; jj < 2; ++jj) {
      const int c = jj * 256 + tid;
      const int r = c >> 2, sl = c & 3;
      gload_lds16(&A[(size_t)(m0 + r) * kE + k0 + sl * 8], &As[c * 8]);
      gload_lds16(&W[(size_t)(n0 + r) * kE + k0 + sl * 8], &Bs[c * 8]);
    }
    __syncthreads();

    bf16x8 af[4], bfr[4];
#pragma unroll
    for (int mi = 0; mi < 4; ++mi)
      af[mi] = *(const bf16x8*)&As[(wm * 64 + mi * 16 + qi) * 32 + g * 8];
#pragma unroll
    for (int nj = 0; nj < 4; ++nj)
      bfr[nj] = *(const bf16x8*)&Bs[(wn * 64 + nj * 16 + qi) * 32 + g * 8];
#pragma unroll
    for (int mi = 0; mi < 4; ++mi)
#pragma unroll
      for (int nj = 0; nj < 4; ++nj)
        acc[mi][nj] = MFMA16(af[mi], bfr[nj], acc[mi][nj]);
    __syncthreads();
  }

  const int bb = m0 >> 11, ss0 = m0 & 2047;
  if (z == 2) {
    // transposed epilogue: Ts used as [64 d][136 s-stride]
#pragma unroll
    for (int half = 0; half < 2; ++half) {
      __syncthreads();
      if (wn == half) {
#pragma unroll
        for (int nj = 0; nj < 4; ++nj) {
          const int dl = nj * 16 + qi;
          const float bn = bias[n0 + half * 64 + dl];
#pragma unroll
          for (int mi = 0; mi < 4; ++mi) {
            const int srow = wm * 64 + mi * 16 + g * 4;
            bf16x4 o;
#pragma unroll
            for (int r = 0; r < 4; ++r) o[r] = (__bf16)(acc[mi][nj][r] + bn);
            *(bf16x4*)&Ts[dl * 136 + srow] = o;
          }
        }
      }
      __syncthreads();
      const int drow = tid >> 2, sc = (tid & 3) * 32;
      const int head = (n0 + half * 64) >> 6;
      __bf16* dst = OutB + (((size_t)bb * kH + head) * kD + drow) * kS + ss0 + sc;
#pragma unroll
      for (int jj = 0; jj < 4; ++jj) {
        bf16x8 vv = *(const bf16x8*)&Ts[drow * 136 + sc + jj * 8];
        *(bf16x8*)&dst[jj * 8] = vv;
      }
    }
    return;
  }

  // z<=1: row-major [B,H,S,D] epilogue via Ts [128 s][72] -> b128 stores
#pragma unroll
  for (int half = 0; half < 2; ++half) {
    __syncthreads();
    if (wn == half) {
#pragma unroll
      for (int nj = 0; nj < 4; ++nj) {
        const int dl = nj * 16 + qi;
        const float bn = bias[n0 + half * 64 + dl];
#pragma unroll
        for (int mi = 0; mi < 4; ++mi) {
          const int srow = wm * 64 + mi * 16 + g * 4;
#pragma unroll
          for (int r = 0; r < 4; ++r)
            Ts[(srow + r) * 72 + dl] = (__bf16)((acc[mi][nj][r] + bn) * scale);
        }
      }
    }
    __syncthreads();
    const int row = tid >> 1, cg = tid & 1;
    const int head = (n0 + half * 64) >> 6;
    __bf16* dst =
        OutB + (((size_t)bb * kH + head) * kS + ss0 + row) * kD + cg * 32;
#pragma unroll
    for (int jj = 0; jj < 4; ++jj)
      *(bf16x8*)&dst[jj * 8] = *(const bf16x8*)&Ts[row * 72 + cg * 32 + jj * 8];
  }
}

// ---------------------------------------------------------------------------
// Kernel 3: out projection, C = A[4096,1024] @ Wo^T + bo -> f32, 128x64 tile
// ---------------------------------------------------------------------------
__global__ __launch_bounds__(256) void gemm_out64(
    const __bf16* __restrict__ A, const __bf16* __restrict__ W,
    const float* __restrict__ bias, float* __restrict__ OF) {
  const int n0 = blockIdx.x * 64;
  const int m0 = blockIdx.y * 128;
  const int tid = threadIdx.x;
  const int wave = tid >> 6, lane = tid & 63;
  const int g = lane >> 4, qi = lane & 15;
  const int wm = wave >> 1, wn = wave & 1;

  __shared__ __align__(16) __bf16 As[128 * 32];
  __shared__ __align__(16) __bf16 Bs[64 * 32];

  f32x4 acc[4][2];
#pragma unroll
  for (int i = 0; i < 4; ++i)
#pragma unroll
    for (int jj = 0; jj < 2; ++jj) acc[i][jj] = (f32x4){0.f, 0.f, 0.f, 0.f};

  for (int k0 = 0; k0 < kE; k0 += 32) {
#pragma unroll
    for (int jj = 0; jj < 2; ++jj) {
      const int c = jj * 256 + tid;
      const int r = c >> 2, sl = c & 3;
      gload_lds16(&A[(size_t)(m0 + r) * kE + k0 + sl * 8], &As[c * 8]);
    }
    {
      const int r = tid >> 2, sl = tid & 3;
      gload_lds16(&W[(size_t)(n0 + r) * kE + k0 + sl * 8], &Bs[tid * 8]);
    }
    __syncthreads();

    bf16x8 af[4], bfr[2];
#pragma unroll
    for (int mi = 0; mi < 4; ++mi)
      af[mi] = *(const bf16x8*)&As[(wm * 64 + mi * 16 + qi) * 32 + g * 8];
#pragma unroll
    for (int nj = 0; nj < 2; ++nj)
      bfr[nj] = *(const bf16x8*)&Bs[(wn * 32 + nj * 16 + qi) * 32 + g * 8];
#pragma unroll
    for (int mi = 0; mi < 4; ++mi)
#pragma unroll
      for (int nj = 0; nj < 2; ++nj)
        acc[mi][nj] = MFMA16(af[mi], bfr[nj], acc[mi][nj]);
    __syncthreads();
  }

#pragma unroll
  for (int nj = 0; nj < 2; ++nj) {
    const int ncol = n0 + wn * 32 + nj * 16 + qi;
    const float bn = bias[ncol];
#pragma unroll
    for (int mi = 0; mi < 4; ++mi)
#pragma unroll
      for (int r = 0; r < 4; ++r) {
        const int mrow = m0 + wm * 64 + mi * 16 + g * 4 + r;
        OF[(size_t)mrow * kE + ncol] = acc[mi][nj][r] + bn;
      }
  }
}

// ---------------------------------------------------------------------------
// Kernel 4: flash attention. 4 waves/block, 32 q-rows/wave (2 q-tiles share
// every K/V fragment read -> LDS traffic per q halved). BK=64 double-buffered
// LDS (both-sides XOR swizzle); t-loop unrolled x2 so all ds_read addresses
// are base + compile-time immediate offsets. Fixed-m exp2 softmax; den via
// ones-MFMA (P row-sum).
// ---------------------------------------------------------------------------
__global__ __launch_bounds__(256, 2) void attn_kernel(
    const __bf16* __restrict__ Qh, const __bf16* __restrict__ Kh,
    const __bf16* __restrict__ Vt, const unsigned long long* __restrict__ mw,
    __bf16* __restrict__ Ob) {
  const int tid = threadIdx.x;
  const int wave = tid >> 6, lane = tid & 63;
  const int g = lane >> 4, qi = lane & 15;
  const int id = blockIdx.x;
  const int xcd = id & 7, j = id >> 3;
  const int bh = xcd * 4 + (j >> 4);
  const int qb = j & 15;
  const int b = bh >> 4, h = bh & 15;

  __shared__ __align__(16) __bf16 Ks[2][64 * 64];
  __shared__ __align__(16) __bf16 Vs[2][64 * 64];

  const __bf16* Qp = Qh + (size_t)bh * kS * kD;
  const __bf16* Kp = Kh + (size_t)bh * kS * kD;
  const __bf16* Vp = Vt + (size_t)bh * kD * kS;

  const int q0 = qb * 128 + wave * 32 + qi;
  const int q1 = q0 + 16;
  const unsigned long long* M0 = mw + (size_t)(b * kS + q0) * kMaskWordsPerRow;
  const unsigned long long* M1 = mw + (size_t)(b * kS + q1) * kMaskWordsPerRow;

  // Q fragments (B-operand); (1/8)*log2e pre-folded into Qh.
  const bf16x8 qf00 = *(const bf16x8*)&Qp[(size_t)q0 * kD + g * 8];
  const bf16x8 qf01 = *(const bf16x8*)&Qp[(size_t)q0 * kD + 32 + g * 8];
  const bf16x8 qf10 = *(const bf16x8*)&Qp[(size_t)q1 * kD + g * 8];
  const bf16x8 qf11 = *(const bf16x8*)&Qp[(size_t)q1 * kD + 32 + g * 8];

  f32x4 acc0[4], acc1[4];
#pragma unroll
  for (int f = 0; f < 4; ++f) {
    acc0[f] = (f32x4){0.f, 0.f, 0.f, 0.f};
    acc1[f] = (f32x4){0.f, 0.f, 0.f, 0.f};
  }
  f32x4 accd0 = (f32x4){0.f, 0.f, 0.f, 0.f};
  f32x4 accd1 = (f32x4){0.f, 0.f, 0.f, 0.f};
  const f32x4 kZero = (f32x4){0.f, 0.f, 0.f, 0.f};
  const float ninf = __builtin_bit_cast(float, 0xff800000u);
  const u32x4 onesu = {0x3F803F80u, 0x3F803F80u, 0x3F803F80u, 0x3F803F80u};
  const bf16x8 vones = __builtin_bit_cast(bf16x8, onesu);

  const int sw = qi & 7;
  // per-thread LDS read bases (bytes); all loop reads are base + imm offset.
  const char* kA = (const char*)&Ks[0][0] + (qi * 64 + ((g ^ sw) * 8)) * 2;
  const char* kBp = (const char*)&Ks[0][0] + (qi * 64 + (((4 + g) ^ sw) * 8)) * 2;
  const char* vA = (const char*)&Vs[0][0] + (qi * 64 + ((g ^ sw) * 8)) * 2;
  const char* vB = (const char*)&Vs[0][0] + (qi * 64 + (((4 + g) ^ sw) * 8)) * 2;

  // stage one BK=64 tile: 512 chunks each of K,V; 2 per thread per array.
  auto stage = [&](int buf, int kv0) {
#pragma unroll
    for (int jj = 0; jj < 2; ++jj) {
      const int c = jj * 256 + tid;
      const int row = c >> 3, sl = c & 7;
      const int sls = sl ^ (row & 7);
      gload_lds16(&Kp[(size_t)(kv0 + row) * kD + sls * 8], &Ks[buf][c * 8]);
      gload_lds16(&Vp[(size_t)row * kS + kv0 + sls * 8], &Vs[buf][c * 8]);
    }
  };

#define ATTN_BODY(BUF, W0, W1)                                                 \
  {                                                                            \
    const unsigned long long w0_ = (W0), w1_ = (W1);                           \
    unsigned wf0_[4], wf1_[4];                                                 \
    {                                                                          \
      const unsigned lo0 = (unsigned)(w0_ >> (g * 4));                         \
      const unsigned hi0 = (unsigned)(w0_ >> (32 + g * 4));                    \
      wf0_[0] = lo0; wf0_[1] = lo0 >> 16; wf0_[2] = hi0; wf0_[3] = hi0 >> 16;  \
      const unsigned lo1 = (unsigned)(w1_ >> (g * 4));                         \
      const unsigned hi1 = (unsigned)(w1_ >> (32 + g * 4));                    \
      wf1_[0] = lo1; wf1_[1] = lo1 >> 16; wf1_[2] = hi1; wf1_[3] = hi1 >> 16;  \
    }                                                                          \
    float p0_[16], p1_[16];                                                    \
    __builtin_amdgcn_s_setprio(1);                                             \
    _Pragma("unroll")                                                          \
    for (int f = 0; f < 4; ++f) {                                              \
      const bf16x8 k0_ = *(const bf16x8*)(kA + (BUF)*8192 + f * 2048);         \
      const bf16x8 k1_ = *(const bf16x8*)(kBp + (BUF)*8192 + f * 2048);        \
      f32x4 st0_ = MFMA16(k0_, qf00, kZero);                                   \
      st0_ = MFMA16(k1_, qf01, st0_);                                          \
      f32x4 st1_ = MFMA16(k0_, qf10, kZero);                                   \
      st1_ = MFMA16(k1_, qf11, st1_);                                          \
      _Pragma("unroll")                                                        \
      for (int r4 = 0; r4 < 4; ++r4) {                                         \
        p0_[4 * f + r4] = (wf0_[f] & (1u << r4)) ? st0_[r4] : ninf;            \
        p1_[4 * f + r4] = (wf1_[f] & (1u << r4)) ? st1_[r4] : ninf;            \
      }                                                                        \
    }                                                                          \
    __builtin_amdgcn_s_setprio(0);                                             \
    _Pragma("unroll")                                                          \
    for (int i = 0; i < 16; ++i) {                                             \
      p0_[i] = EXP2(p0_[i]);                                                   \
      p1_[i] = EXP2(p1_[i]);                                                   \
    }                                                                          \
    unsigned pk0_[4][2], pk1_[4][2];                                           \
    _Pragma("unroll")                                                          \
    for (int f = 0; f < 4; ++f) {                                              \
      pk0_[f][0] = pack_bf16x2(p0_[4 * f + 0], p0_[4 * f + 1]);                \
      pk0_[f][1] = pack_bf16x2(p0_[4 * f + 2], p0_[4 * f + 3]);                \
      pk1_[f][0] = pack_bf16x2(p1_[4 * f + 0], p1_[4 * f + 1]);                \
      pk1_[f][1] = pack_bf16x2(p1_[4 * f + 2], p1_[4 * f + 3]);                \
    }                                                                          \
    _Pragma("unroll")                                                          \
    for (int c = 0; c < 2; ++c) {                                              \
      unsigned bw0_[4], bw1_[4];                                               \
      _Pragma("unroll")                                                        \
      for (int t4 = 0; t4 < 4; ++t4) {                                         \
        const int src_ = qi + 16 * ((t4 >> 1) + 2 * (g & 1));                  \
        const int a0_ = __shfl((int)pk0_[2 * c + 0][t4 & 1], src_);            \
        const int b0_ = __shfl((int)pk0_[2 * c + 1][t4 & 1], src_);            \
        bw0_[t4] = (g >= 2) ? (unsigned)b0_ : (unsigned)a0_;                   \
        const int a1_ = __shfl((int)pk1_[2 * c + 0][t4 & 1], src_);            \
        const int b1_ = __shfl((int)pk1_[2 * c + 1][t4 & 1], src_);            \
        bw1_[t4] = (g >= 2) ? (unsigned)b1_ : (unsigned)a1_;                   \
      }                                                                        \
      const u32x4 u0_ = {bw0_[0], bw0_[1], bw0_[2], bw0_[3]};                  \
      const u32x4 u1_ = {bw1_[0], bw1_[1], bw1_[2], bw1_[3]};                  \
      const bf16x8 pb0_ = __builtin_bit_cast(bf16x8, u0_);                     \
      const bf16x8 pb1_ = __builtin_bit_cast(bf16x8, u1_);                     \
      __builtin_amdgcn_s_setprio(1);                                           \
      _Pragma("unroll")                                                        \
      for (int f = 0; f < 4; ++f) {                                            \
        const bf16x8 vf_ = (c == 0)                                            \
            ? *(const bf16x8*)(vA + (BUF)*8192 + f * 2048)                     \
            : *(const bf16x8*)(vB + (BUF)*8192 + f * 2048);                    \
        acc0[f] = MFMA16(vf_, pb0_, acc0[f]);                                  \
        acc1[f] = MFMA16(vf_, pb1_, acc1[f]);                                  \
      }                                                                        \
      accd0 = MFMA16(vones, pb0_, accd0);                                      \
      accd1 = MFMA16(vones, pb1_, accd1);                                      \
      __builtin_amdgcn_s_setprio(0);                                           \
    }                                                                          \
  }

  stage(0, 0);
  __syncthreads();

#pragma unroll 1
  for (int tt = 0; tt < 16; ++tt) {
    const ulonglong2 w0p = *(const ulonglong2*)&M0[2 * tt];
    const ulonglong2 w1p = *(const ulonglong2*)&M1[2 * tt];
    stage(1, (2 * tt + 1) * 64);
    ATTN_BODY(0, w0p.x, w1p.x);
    __syncthreads();
    if (tt < 15) stage(0, (2 * tt + 2) * 64);
    ATTN_BODY(1, w0p.y, w1p.y);
    __syncthreads();
  }
#undef ATTN_BODY

  const float ri0 = 1.0f / accd0[0];
  const float ri1 = 1.0f / accd1[0];
  __bf16* Op0 = Ob + (size_t)(b * kS + q0) * kE + h * kD;
  __bf16* Op1 = Ob + (size_t)(b * kS + q1) * kE + h * kD;
#pragma unroll
  for (int f = 0; f < 4; ++f) {
    ushort4 o0, o1;
    o0.x = __builtin_bit_cast(unsigned short, (__bf16)(acc0[f][0] * ri0));
    o0.y = __builtin_bit_cast(unsigned short, (__bf16)(acc0[f][1] * ri0));
    o0.z = __builtin_bit_cast(unsigned short, (__bf16)(acc0[f][2] * ri0));
    o0.w = __builtin_bit_cast(unsigned short, (__bf16)(acc0[f][3] * ri0));
    *(ushort4*)&Op0[f * 16 + g * 4] = o0;
    o1.x = __builtin_bit_cast(unsigned short, (__bf16)(acc1[f][0] * ri1));
    o1.y = __builtin_bit_cast(unsigned short, (__bf16)(acc1[f][1] * ri1));
    o1.z = __builtin_bit_cast(unsigned short, (__bf16)(acc1[f][2] * ri1));
    o1.w = __builtin_bit_cast(unsigned short, (__bf16)(acc1[f][3] * ri1));
    *(ushort4*)&Op1[f * 16 + g * 4] = o1;
  }
}

// ---------------------------------------------------------------------------
extern "C" void kernel_launch(void* const* d_in, const int* in_sizes, int n_in,
                              void* d_out, int out_size, void* d_ws, size_t ws_size,
                              hipStream_t stream) {
  (void)in_sizes; (void)n_in; (void)out_size; (void)ws_size;
  const float* q  = (const float*)d_in[0];
  const float* k  = (const float*)d_in[1];
  const float* v  = (const float*)d_in[2];
  const int*   mask = (const int*)d_in[3];
  const float* Wq = (const float*)d_in[4];
  const float* bq = (const float*)d_in[5];
  const float* Wk = (const float*)d_in[6];
  const float* bk = (const float*)d_in[7];
  const float* Wv = (const float*)d_in[8];
  const float* bv = (const float*)d_in[9];
  const float* Wo = (const float*)d_in[10];
  const float* bo = (const float*)d_in[11];

  char* ws = (char*)d_ws;
  const size_t MB = 1024 * 1024;
  __bf16* qb  = (__bf16*)(ws + 0 * MB);    // 8MB  [4096,1024]
  __bf16* kb  = (__bf16*)(ws + 8 * MB);    // 8MB
  __bf16* vb  = (__bf16*)(ws + 16 * MB);   // 8MB
  __bf16* wqb = (__bf16*)(ws + 24 * MB);   // 2MB
  __bf16* wkb = (__bf16*)(ws + 26 * MB);   // 2MB
  __bf16* wvb = (__bf16*)(ws + 28 * MB);   // 2MB
  __bf16* wob = (__bf16*)(ws + 30 * MB);   // 2MB
  __bf16* Qh  = (__bf16*)(ws + 32 * MB);   // 8MB [B,H,S,D]
  __bf16* Kh  = (__bf16*)(ws + 40 * MB);   // 8MB [B,H,S,D]
  __bf16* Vt  = (__bf16*)(ws + 48 * MB);   // 8MB [B,H,D,S]
  unsigned long long* mwords = (unsigned long long*)(ws + 56 * MB);  // 1MB
  __bf16* Ob = qb;   // qb dead after QKV GEMM

  cvt_pack_kernel<<<kCvtBlocks, 256, 0, stream>>>(
      q, k, v, Wq, Wk, Wv, Wo, mask, qb, kb, vb, wqb, wkb, wvb, wob, mwords);
  gemm_bt<<<dim3(8, 32, 3), 256, 0, stream>>>(qb, kb, vb, wqb, wkb, wvb,
                                              bq, bk, bv, Qh, Kh, Vt);
  attn_kernel<<<512, 256, 0, stream>>>(Qh, Kh, Vt, mwords, Ob);
  gemm_out64<<<dim3(16, 32), 256, 0, stream>>>(Ob, wob, bo, (float*)d_out);
}